// Round 1
// baseline (51.913 us; speedup 1.0000x reference)
//
#include <hip/hip_runtime.h>
#include <math.h>

#define N_NODES 10000
#define N_REL   500
#define H       128
#define L       128

#define TL 64   // l-tile
#define TN 64   // n-tile
#define HC 64   // h-chunk

__device__ __forceinline__ float waveReduceSum(float v) {
    #pragma unroll
    for (int m = 1; m < 64; m <<= 1) v += __shfl_xor(v, m, 64);
    return v;
}

// --- kernel 1: inverse L2 norm of every node row ---------------------------
// one wave per row; lane loads float2 (2 elems), 64 lanes cover H=128
__global__ __launch_bounds__(256) void k_invnorm(const float* __restrict__ node,
                                                 float* __restrict__ invn) {
    int wave = threadIdx.x >> 6;
    int lane = threadIdx.x & 63;
    int row  = blockIdx.x * 4 + wave;
    if (row >= N_NODES) return;
    float2 v = *reinterpret_cast<const float2*>(node + row * H + lane * 2);
    float ss = waveReduceSum(v.x * v.x + v.y * v.y);
    if (lane == 0) invn[row] = 1.0f / fmaxf(sqrtf(ss), 1e-12f);
}

// --- kernel 2: query rows = norm(node[ent]) + norm(rel[rel]) ---------------
__global__ __launch_bounds__(256) void k_query(const float* __restrict__ node,
                                               const float* __restrict__ rel,
                                               const int* __restrict__ eidx,
                                               const int* __restrict__ ridx,
                                               float* __restrict__ query) {
    int wave = threadIdx.x >> 6;
    int lane = threadIdx.x & 63;
    int l = blockIdx.x * 4 + wave;
    if (l >= L) return;
    int ei = eidx[l], ri = ridx[l];
    float2 e = *reinterpret_cast<const float2*>(node + ei * H + lane * 2);
    float inve = 1.0f / fmaxf(sqrtf(waveReduceSum(e.x * e.x + e.y * e.y)), 1e-12f);
    float2 r = *reinterpret_cast<const float2*>(rel + ri * H + lane * 2);
    float invr = 1.0f / fmaxf(sqrtf(waveReduceSum(r.x * r.x + r.y * r.y)), 1e-12f);
    float2 q;
    q.x = e.x * inve + r.x * invr;
    q.y = e.y * inve + r.y * invr;
    *reinterpret_cast<float2*>(query + l * H + lane * 2) = q;
}

// --- kernel 3: dist[l,n] = sum_h |query[l,h] - node[n,h]*invn[n]| ----------
// LDS tiles stored [h][l] with XOR swizzle (l ^ (h&60)) -> <=2-way conflicts
__global__ __launch_bounds__(256) void k_dist(const float* __restrict__ node,
                                              const float* __restrict__ invn,
                                              const float* __restrict__ query,
                                              float* __restrict__ out) {
    __shared__ float qs[HC * TL];
    __shared__ float es[HC * TN];

    int nb = blockIdx.x * TN;
    int lb = blockIdx.y * TL;
    int tid = threadIdx.x;
    int tl = tid >> 4;   // 0..15  -> l sub-tile
    int tn = tid & 15;   // 0..15  -> n sub-tile

    float acc[4][4] = {};

    for (int hb = 0; hb < H; hb += HC) {
        // stage q tile: TL x HC floats, transpose into [h][l] w/ swizzle
        #pragma unroll
        for (int k = 0; k < 4; ++k) {
            int f  = tid + (k << 8);        // float4 index within tile
            int r  = f >> 4;                // row (l within tile)
            int c4 = (f & 15) << 2;         // h offset within chunk
            float4 v = *reinterpret_cast<const float4*>(query + (lb + r) * H + hb + c4);
            int rs = r ^ c4;                // (c4+c)&60 == c4 for c in 0..3
            qs[(c4 + 0) * TL + rs] = v.x;
            qs[(c4 + 1) * TL + rs] = v.y;
            qs[(c4 + 2) * TL + rs] = v.z;
            qs[(c4 + 3) * TL + rs] = v.w;
        }
        // stage e tile (pre-scaled by inverse norm)
        #pragma unroll
        for (int k = 0; k < 4; ++k) {
            int f  = tid + (k << 8);
            int r  = f >> 4;
            int c4 = (f & 15) << 2;
            int gn = nb + r;
            float4 v = make_float4(0.f, 0.f, 0.f, 0.f);
            float s = 0.f;
            if (gn < N_NODES) {
                v = *reinterpret_cast<const float4*>(node + gn * H + hb + c4);
                s = invn[gn];
            }
            int rs = r ^ c4;
            es[(c4 + 0) * TN + rs] = v.x * s;
            es[(c4 + 1) * TN + rs] = v.y * s;
            es[(c4 + 2) * TN + rs] = v.z * s;
            es[(c4 + 3) * TN + rs] = v.w * s;
        }
        __syncthreads();

        #pragma unroll
        for (int h = 0; h < HC; ++h) {
            int sw = h & 60;
            float4 q4 = *reinterpret_cast<const float4*>(&qs[h * TL + ((tl << 2) ^ sw)]);
            float4 e4 = *reinterpret_cast<const float4*>(&es[h * TN + ((tn << 2) ^ sw)]);
            float qa[4] = {q4.x, q4.y, q4.z, q4.w};
            float ea[4] = {e4.x, e4.y, e4.z, e4.w};
            #pragma unroll
            for (int i = 0; i < 4; ++i)
                #pragma unroll
                for (int j = 0; j < 4; ++j)
                    acc[i][j] += fabsf(qa[i] - ea[j]);
        }
        __syncthreads();
    }

    // write 4x4 tile; n-groups of 4 are fully valid or fully invalid (N%16==0... N=10000, nb mult 64)
    int n0 = nb + (tn << 2);
    if (n0 < N_NODES) {
        #pragma unroll
        for (int i = 0; i < 4; ++i) {
            int l = lb + (tl << 2) + i;
            float4 v = make_float4(acc[i][0], acc[i][1], acc[i][2], acc[i][3]);
            *reinterpret_cast<float4*>(out + (size_t)l * N_NODES + n0) = v;
        }
    }
}

// --- kernel 4: in-place row softmax over N_NODES ---------------------------
__global__ __launch_bounds__(256) void k_softmax(float* __restrict__ out) {
    __shared__ float sd[N_NODES];   // 40000 B
    __shared__ float red[8];
    int tid = threadIdx.x;
    int wave = tid >> 6, lane = tid & 63;
    float* p = out + (size_t)blockIdx.x * N_NODES;

    float lmax = -INFINITY;
    for (int i = tid; i < N_NODES; i += 256) {
        float v = p[i];
        sd[i] = v;
        lmax = fmaxf(lmax, v);
    }
    #pragma unroll
    for (int m = 1; m < 64; m <<= 1) lmax = fmaxf(lmax, __shfl_xor(lmax, m, 64));
    if (lane == 0) red[wave] = lmax;
    __syncthreads();
    float bmax = fmaxf(fmaxf(red[0], red[1]), fmaxf(red[2], red[3]));

    float lsum = 0.f;
    for (int i = tid; i < N_NODES; i += 256) {
        float e = expf(sd[i] - bmax);
        sd[i] = e;
        lsum += e;
    }
    #pragma unroll
    for (int m = 1; m < 64; m <<= 1) lsum += __shfl_xor(lsum, m, 64);
    if (lane == 0) red[4 + wave] = lsum;
    __syncthreads();
    float inv = 1.0f / (red[4] + red[5] + red[6] + red[7]);

    for (int i = tid; i < N_NODES; i += 256) p[i] = sd[i] * inv;
}

extern "C" void kernel_launch(void* const* d_in, const int* in_sizes, int n_in,
                              void* d_out, int out_size, void* d_ws, size_t ws_size,
                              hipStream_t stream) {
    const float* node = (const float*)d_in[0];
    const float* rel  = (const float*)d_in[1];
    const int*   eidx = (const int*)d_in[2];
    const int*   ridx = (const int*)d_in[3];
    float* out = (float*)d_out;

    float* invn  = (float*)d_ws;            // N_NODES floats = 40 KB
    float* query = (float*)d_ws + 10240;    // 128*128 floats = 64 KB (offset 40960 B)

    k_invnorm<<<(N_NODES + 3) / 4, 256, 0, stream>>>(node, invn);
    k_query<<<(L + 3) / 4, 256, 0, stream>>>(node, rel, eidx, ridx, query);

    dim3 grid((N_NODES + TN - 1) / TN, L / TL);   // 157 x 2
    k_dist<<<grid, 256, 0, stream>>>(node, invn, query, out);

    k_softmax<<<L, 256, 0, stream>>>(out);
}

// Round 2
// 31.730 us; speedup vs baseline: 1.6361x; 1.6361x over previous
//
#include <hip/hip_runtime.h>
#include <math.h>

#define N_NODES 10000
#define N_REL   500
#define H       128
#define L       128

#define TL 32    // l-tile
#define TN 64    // n-tile
#define HC 64    // h-chunk
#define NB 157   // number of n-blocks = ceil(10000/64)

__device__ __forceinline__ float waveReduceSum(float v) {
    #pragma unroll
    for (int m = 1; m < 64; m <<= 1) v += __shfl_xor(v, m, 64);
    return v;
}

// --- kernel A: per-node inverse norms (blocks 0..2499) + query rows (2500..2531)
__global__ __launch_bounds__(256) void k_prep(const float* __restrict__ node,
                                              const float* __restrict__ rel,
                                              const int* __restrict__ eidx,
                                              const int* __restrict__ ridx,
                                              float* __restrict__ invn,
                                              float* __restrict__ query) {
    int wave = threadIdx.x >> 6;
    int lane = threadIdx.x & 63;
    if (blockIdx.x < 2500) {
        int row = blockIdx.x * 4 + wave;            // < 10000 always
        float2 v = *reinterpret_cast<const float2*>(node + row * H + lane * 2);
        float ss = waveReduceSum(v.x * v.x + v.y * v.y);
        if (lane == 0) invn[row] = 1.0f / fmaxf(sqrtf(ss), 1e-12f);
    } else {
        int l = (blockIdx.x - 2500) * 4 + wave;     // < 128 always
        int ei = eidx[l], ri = ridx[l];
        float2 e = *reinterpret_cast<const float2*>(node + ei * H + lane * 2);
        float inve = 1.0f / fmaxf(sqrtf(waveReduceSum(e.x * e.x + e.y * e.y)), 1e-12f);
        float2 r = *reinterpret_cast<const float2*>(rel + ri * H + lane * 2);
        float invr = 1.0f / fmaxf(sqrtf(waveReduceSum(r.x * r.x + r.y * r.y)), 1e-12f);
        float2 q;
        q.x = e.x * inve + r.x * invr;
        q.y = e.y * inve + r.y * invr;
        *reinterpret_cast<float2*>(query + l * H + lane * 2) = q;
    }
}

// --- kernel B: dist tile + tile-local softmax partials --------------------
// out[l,n] = exp(dist - pmax[l,nblk]);  pmax/psum per (l, nblk) into ws
__global__ __launch_bounds__(256) void k_dist(const float* __restrict__ node,
                                              const float* __restrict__ invn,
                                              const float* __restrict__ query,
                                              float* __restrict__ out,
                                              float* __restrict__ pmax,
                                              float* __restrict__ psum) {
    __shared__ float qs[HC * TL];   // [h][l], swizzled
    __shared__ float es[HC * TN];   // [h][n], swizzled, pre-scaled by invn

    int nb = blockIdx.x * TN;
    int lb = blockIdx.y * TL;
    int tid = threadIdx.x;
    int tl = tid >> 4;   // 0..15 -> 2 l-rows each
    int tn = tid & 15;   // 0..15 -> 4 n-cols each

    float acc[2][4] = {};

    for (int hb = 0; hb < H; hb += HC) {
        // stage q tile: TL(32) x HC(64) = 512 float4, 2 per thread
        #pragma unroll
        for (int k = 0; k < 2; ++k) {
            int f  = tid + (k << 8);
            int r  = f >> 4;               // 0..31
            int c4 = (f & 15) << 2;        // 0..60
            float4 v = *reinterpret_cast<const float4*>(query + (lb + r) * H + hb + c4);
            int rs = r ^ (c4 & 28);        // < 32
            qs[(c4 + 0) * TL + rs] = v.x;
            qs[(c4 + 1) * TL + rs] = v.y;
            qs[(c4 + 2) * TL + rs] = v.z;
            qs[(c4 + 3) * TL + rs] = v.w;
        }
        // stage e tile: TN(64) x HC(64) = 1024 float4, 4 per thread
        #pragma unroll
        for (int k = 0; k < 4; ++k) {
            int f  = tid + (k << 8);
            int r  = f >> 4;               // 0..63
            int c4 = (f & 15) << 2;
            int gn = nb + r;
            float4 v = make_float4(0.f, 0.f, 0.f, 0.f);
            float s = 0.f;
            if (gn < N_NODES) {
                v = *reinterpret_cast<const float4*>(node + gn * H + hb + c4);
                s = invn[gn];
            }
            int rs = r ^ (c4 & 60);        // < 64
            es[(c4 + 0) * TN + rs] = v.x * s;
            es[(c4 + 1) * TN + rs] = v.y * s;
            es[(c4 + 2) * TN + rs] = v.z * s;
            es[(c4 + 3) * TN + rs] = v.w * s;
        }
        __syncthreads();

        #pragma unroll
        for (int h = 0; h < HC; ++h) {
            float2 q2 = *reinterpret_cast<const float2*>(&qs[h * TL + ((tl << 1) ^ (h & 28))]);
            float4 e4 = *reinterpret_cast<const float4*>(&es[h * TN + ((tn << 2) ^ (h & 60))]);
            float qa[2] = {q2.x, q2.y};
            float ea[4] = {e4.x, e4.y, e4.z, e4.w};
            #pragma unroll
            for (int i = 0; i < 2; ++i)
                #pragma unroll
                for (int j = 0; j < 4; ++j)
                    acc[i][j] += fabsf(qa[i] - ea[j]);
        }
        __syncthreads();
    }

    // --- tile-local softmax partials ---
    int n0 = nb + (tn << 2);
    bool valid = n0 < N_NODES;   // N%4==0 and per-4 groups all-or-nothing

    float rmax[2], rsum[2];
    #pragma unroll
    for (int i = 0; i < 2; ++i) {
        float m = valid ? fmaxf(fmaxf(acc[i][0], acc[i][1]), fmaxf(acc[i][2], acc[i][3]))
                        : -INFINITY;
        #pragma unroll
        for (int s = 1; s < 16; s <<= 1) m = fmaxf(m, __shfl_xor(m, s, 64));
        rmax[i] = m;   // tn 0..3 of every row-group is always valid -> finite
        float p[4], sum = 0.f;
        #pragma unroll
        for (int j = 0; j < 4; ++j) {
            p[j] = valid ? expf(acc[i][j] - m) : 0.f;
            sum += p[j];
        }
        #pragma unroll
        for (int s = 1; s < 16; s <<= 1) sum += __shfl_xor(sum, s, 64);
        rsum[i] = sum;
        if (valid) {
            int l = lb + (tl << 1) + i;
            *reinterpret_cast<float4*>(out + (size_t)l * N_NODES + n0) =
                make_float4(p[0], p[1], p[2], p[3]);
        }
    }
    if (tn == 0) {
        #pragma unroll
        for (int i = 0; i < 2; ++i) {
            int l = lb + (tl << 1) + i;
            pmax[l * NB + blockIdx.x] = rmax[i];
            psum[l * NB + blockIdx.x] = rsum[i];
        }
    }
}

// --- kernel D: finish softmax: redundant per-row partial reduce + scale ---
__global__ __launch_bounds__(256) void k_finish(float* __restrict__ out,
                                                const float* __restrict__ pmax,
                                                const float* __restrict__ psum) {
    __shared__ float red[8];
    int l = blockIdx.y;
    int tid = threadIdx.x;
    const float* pm = pmax + l * NB;
    const float* ps = psum + l * NB;

    float m = (tid < NB) ? pm[tid] : -INFINITY;
    #pragma unroll
    for (int s = 1; s < 64; s <<= 1) m = fmaxf(m, __shfl_xor(m, s, 64));
    if ((tid & 63) == 0) red[tid >> 6] = m;
    __syncthreads();
    float gmax = fmaxf(fmaxf(red[0], red[1]), fmaxf(red[2], red[3]));

    float sum = (tid < NB) ? ps[tid] * expf(pm[tid] - gmax) : 0.f;
    #pragma unroll
    for (int s = 1; s < 64; s <<= 1) sum += __shfl_xor(sum, s, 64);
    if ((tid & 63) == 0) red[4 + (tid >> 6)] = sum;
    __syncthreads();
    float inv = 1.0f / (red[4] + red[5] + red[6] + red[7]);

    int n4 = blockIdx.x * 256 + tid;           // float4 index within row
    if (n4 < 2500) {
        int blk = n4 >> 4;                     // 64-col block
        float f = expf(pm[blk] - gmax) * inv;
        float4* o = reinterpret_cast<float4*>(out) + (size_t)l * 2500 + n4;
        float4 v = *o;
        v.x *= f; v.y *= f; v.z *= f; v.w *= f;
        *o = v;
    }
}

extern "C" void kernel_launch(void* const* d_in, const int* in_sizes, int n_in,
                              void* d_out, int out_size, void* d_ws, size_t ws_size,
                              hipStream_t stream) {
    const float* node = (const float*)d_in[0];
    const float* rel  = (const float*)d_in[1];
    const int*   eidx = (const int*)d_in[2];
    const int*   ridx = (const int*)d_in[3];
    float* out = (float*)d_out;

    float* invn  = (float*)d_ws;              // 10000 floats
    float* query = (float*)d_ws + 10240;      // 16384 floats
    float* pmax  = (float*)d_ws + 26624;      // 128*157 = 20096 floats
    float* psum  = (float*)d_ws + 46720;      // 20096 floats

    k_prep<<<2532, 256, 0, stream>>>(node, rel, eidx, ridx, invn, query);

    dim3 gridB(NB, L / TL);                   // 157 x 4
    k_dist<<<gridB, 256, 0, stream>>>(node, invn, query, out, pmax, psum);

    dim3 gridD((2500 + 255) / 256, L);        // 10 x 128
    k_finish<<<gridD, 256, 0, stream>>>(out, pmax, psum);
}